// Round 12
// baseline (345.880 us; speedup 1.0000x reference)
//
#include <hip/hip_runtime.h>
#include <math.h>

#define NG 8
#define SEQ 4096
#define DM 1024
#define NE 64
#define GS (NG * SEQ)          // 32768 tokens
#define KSEL 1024              // expert capacity
#define MASK_ELEMS (NE * GS)   // 2097152
#define SEG 16
#define SEGLEN (GS / SEG)
#define CAP 2048               // max repair candidates per expert
#define AST 40                 // A-plane LDS row stride in ushorts (>=32, 16B-aligned rows)

typedef __attribute__((ext_vector_type(8))) short short8;
typedef __attribute__((ext_vector_type(4))) float f32x4;

__device__ __forceinline__ unsigned short f2bf(float v) {   // RN-even
  unsigned u = __float_as_uint(v);
  return (unsigned short)((u + 0x7FFFu + ((u >> 16) & 1u)) >> 16);
}
__device__ __forceinline__ float bf2f(unsigned short h) {
  return __uint_as_float(((unsigned)h) << 16);
}

// ---------------- Kernel 0: pre-split gate weights into 3 transposed bf16 planes --
__global__ __launch_bounds__(256)
void k_split(const float* __restrict__ w, unsigned short* __restrict__ wph,
             unsigned short* __restrict__ wpm, unsigned short* __restrict__ wpl) {
  const int t = blockIdx.x * 256 + threadIdx.x;   // 65536 = 1024k x 64e
  const int k = t >> 6, e = t & 63;
  float v = w[t];
  unsigned short h = f2bf(v); float r = v - bf2f(h);
  unsigned short m = f2bf(r); float r2 = r - bf2f(m);
  unsigned short l = f2bf(r2);
  const int o = e * 1024 + k;                      // transposed [e][k]
  wph[o] = h; wpm[o] = m; wpl[o] = l;
}

// ---------------- Kernel 1: bf16x3 MFMA GEMM (fp64 hi-term accum) + fp64 softmax --
// 1 wave/block, 16 tokens x 64 experts. A rows are 32 bf16; LDS row stride AST=40
// (the rounds-10/11 bug was stride 24 < 32: rows overlapped -> garbage logits).
__global__ __launch_bounds__(64, 2)
void k_gemm_softmax(const float* __restrict__ x,
                    const unsigned short* __restrict__ wph,
                    const unsigned short* __restrict__ wpm,
                    const unsigned short* __restrict__ wpl,
                    const float* __restrict__ bias, const float* __restrict__ temp,
                    float* __restrict__ probsT) {
  __shared__ __align__(16) unsigned short Ah[2][16 * AST], Am[2][16 * AST],
      Al[2][16 * AST];
  __shared__ double Lt[16][65];
  __shared__ float Pt[64][20];

  const int lane = threadIdx.x;
  const int lrow = lane & 15;          // A-row / B-col / D-col
  const int g = lane >> 4;             // k-slot group (8 k each)
  const int m0 = blockIdx.x * 16;

  // --- probes: C/D (lane,reg)->(i,j) for mfma_f32_16x16x32_bf16 (exact ints) ---
  int irow[4], jcol[4];
  {
    union { unsigned short u[8]; short8 v; } ar, on;
#pragma unroll
    for (int j = 0; j < 8; ++j) { ar.u[j] = f2bf((float)lrow); on.u[j] = 0x3F80u; }
    f32x4 z = {0.f, 0.f, 0.f, 0.f};
    f32x4 p1 = __builtin_amdgcn_mfma_f32_16x16x32_bf16(ar.v, on.v, z, 0, 0, 0);
    f32x4 p2 = __builtin_amdgcn_mfma_f32_16x16x32_bf16(on.v, ar.v, z, 0, 0, 0);
#pragma unroll
    for (int b = 0; b < 4; ++b) {
      irow[b] = ((int)p1[b]) >> 5;   // D = 32*i
      jcol[b] = ((int)p2[b]) >> 5;   // D = 32*j
    }
  }

  double acc64[4][4];                  // [cb][reg] hi-term accumulation (fp64)
  f32x4 acc32[4];                      // minor terms (scale <= 2^-9)
#pragma unroll
  for (int cb = 0; cb < 4; ++cb) {
    acc32[cb] = (f32x4){0.f, 0.f, 0.f, 0.f};
#pragma unroll
    for (int b = 0; b < 4; ++b) acc64[cb][b] = 0.0;
  }

  float4 rA0, rA1;
  const int arow = lane >> 2, af = lane & 3;     // A staging decode (8 consec k)
  const int aoff = arow * AST + af * 8;          // ushort elem offset (16B aligned)
  const int foff = lrow * AST + g * 8;           // A-frag read offset
  const int boff = lrow * 1024 + g * 8;          // B plane base (cb adds 16*1024)

#define LOADA(t)                                                                     \
  {                                                                                  \
    const float* ap = x + (size_t)(m0 + arow) * DM + (t) * 32 + af * 8;              \
    rA0 = *(const float4*)ap;                                                        \
    rA1 = *(const float4*)(ap + 4);                                                  \
  }

#define SPLITA(bi)                                                                   \
  {                                                                                  \
    union { float4 f[2]; float s[8]; } qa;                                           \
    qa.f[0] = rA0; qa.f[1] = rA1;                                                    \
    union { unsigned short u[8]; short8 v; } ph, pm, pl;                             \
    _Pragma("unroll")                                                                \
    for (int j = 0; j < 8; ++j) {                                                    \
      float v0 = qa.s[j];                                                            \
      unsigned short h_ = f2bf(v0); float r_ = v0 - bf2f(h_);                        \
      unsigned short mm = f2bf(r_); float r2_ = r_ - bf2f(mm);                       \
      ph.u[j] = h_; pm.u[j] = mm; pl.u[j] = f2bf(r2_);                               \
    }                                                                                \
    *(short8*)(&Ah[bi][aoff]) = ph.v;                                                \
    *(short8*)(&Am[bi][aoff]) = pm.v;                                                \
    *(short8*)(&Al[bi][aoff]) = pl.v;                                                \
  }

#define MFMA_TILE(bi, t)                                                             \
  {                                                                                  \
    short8 ah_ = *(const short8*)(&Ah[bi][foff]);                                    \
    short8 am_ = *(const short8*)(&Am[bi][foff]);                                    \
    short8 al_ = *(const short8*)(&Al[bi][foff]);                                    \
    __builtin_amdgcn_s_setprio(1);                                                   \
    _Pragma("unroll")                                                                \
    for (int cb = 0; cb < 4; ++cb) {                                                 \
      const size_t bo = (size_t)boff + cb * 16 * 1024 + (t) * 32;                    \
      short8 bh_ = *(const short8*)(wph + bo);                                       \
      short8 bm_ = *(const short8*)(wpm + bo);                                       \
      short8 bl_ = *(const short8*)(wpl + bo);                                       \
      f32x4 z_ = {0.f, 0.f, 0.f, 0.f};                                               \
      f32x4 thi = __builtin_amdgcn_mfma_f32_16x16x32_bf16(ah_, bh_, z_, 0, 0, 0);    \
      acc32[cb] = __builtin_amdgcn_mfma_f32_16x16x32_bf16(al_, bh_, acc32[cb], 0, 0, 0); \
      acc32[cb] = __builtin_amdgcn_mfma_f32_16x16x32_bf16(am_, bm_, acc32[cb], 0, 0, 0); \
      acc32[cb] = __builtin_amdgcn_mfma_f32_16x16x32_bf16(ah_, bl_, acc32[cb], 0, 0, 0); \
      acc32[cb] = __builtin_amdgcn_mfma_f32_16x16x32_bf16(am_, bh_, acc32[cb], 0, 0, 0); \
      acc32[cb] = __builtin_amdgcn_mfma_f32_16x16x32_bf16(ah_, bm_, acc32[cb], 0, 0, 0); \
      _Pragma("unroll")                                                              \
      for (int b = 0; b < 4; ++b) acc64[cb][b] += (double)thi[b];                    \
    }                                                                                \
    __builtin_amdgcn_s_setprio(0);                                                   \
  }

  LOADA(0);
  SPLITA(0);
  LOADA(1);

  for (int tt = 0; tt < 32; tt += 2) {
    SPLITA(1);                       // stage tile tt+1 (from rA)
    if (tt + 2 < 32) LOADA(tt + 2);  // global prefetch under MFMA
    MFMA_TILE(0, tt);
    if (tt + 2 < 32) {
      SPLITA(0);                     // stage tile tt+2
      LOADA(tt + 3);
    }
    MFMA_TILE(1, tt + 1);
  }

#undef LOADA
#undef SPLITA
#undef MFMA_TILE

  // --- canonical Lt[token][expert] (fp64) via probe-measured mapping ---
#pragma unroll
  for (int cb = 0; cb < 4; ++cb)
#pragma unroll
    for (int b = 0; b < 4; ++b)
      Lt[irow[b]][cb * 16 + jcol[b]] = acc64[cb][b] + (double)acc32[cb][b];

  // --- fp64 softmax ---
  {
    double st = (double)temp[0];
    if (st < 0.1) st = 0.1;
    const double inv_t = 1.0 / st;
    const int tt = lane >> 2, q = lane & 3;
    double l[16];
    double mx = -1.0e300;
#pragma unroll
    for (int j = 0; j < 16; ++j) {
      l[j] = (Lt[tt][q * 16 + j] + (double)bias[q * 16 + j]) * inv_t;
      mx = fmax(mx, l[j]);
    }
    mx = fmax(mx, __shfl_xor(mx, 1));
    mx = fmax(mx, __shfl_xor(mx, 2));
    double p[16], s = 0.0;
#pragma unroll
    for (int j = 0; j < 16; ++j) { p[j] = exp(l[j] - mx); s += p[j]; }
    s += __shfl_xor(s, 1);
    s += __shfl_xor(s, 2);
    const double invs = 1.0 / s;
#pragma unroll
    for (int j = 0; j < 16; ++j) Pt[q * 16 + j][tt] = (float)(p[j] * invs);
  }

  // --- expert-major store: lane = expert ---
  {
#pragma unroll
    for (int c2 = 0; c2 < 4; ++c2) {
      *(float4*)(probsT + (size_t)lane * GS + m0 + c2 * 4) =
          *(const float4*)(&Pt[lane][c2 * 4]);
    }
  }
}

// ------------- cooperative bucket pick from a 256-bin histogram (block-wide) ------
__device__ __forceinline__ void pick_scan(const unsigned* __restrict__ bins,
                                          unsigned r_in, unsigned& bucket,
                                          unsigned& r_out, unsigned* res) {
  __syncthreads();
  const int tid = threadIdx.x;
  if (tid < 64) {
    uint4 b = ((const uint4*)bins)[tid];
    unsigned s3 = b.w, s2 = b.z + s3, s1 = b.y + s2, s0 = b.x + s1;
    unsigned suf = s0;
#pragma unroll
    for (int off = 1; off < 64; off <<= 1) {
      unsigned t = __shfl_down(suf, off);
      if (tid + off < 64) suf += t;
    }
    unsigned above = suf - s0;
    unsigned inc0 = above + s0, inc1 = above + s1, inc2 = above + s2, inc3 = above + s3;
    if (inc3 >= r_in && inc3 - b.w < r_in) { res[0] = 4 * tid + 3; res[1] = r_in - (inc3 - b.w); }
    if (inc2 >= r_in && inc2 - b.z < r_in) { res[0] = 4 * tid + 2; res[1] = r_in - (inc2 - b.z); }
    if (inc1 >= r_in && inc1 - b.y < r_in) { res[0] = 4 * tid + 1; res[1] = r_in - (inc1 - b.y); }
    if (inc0 >= r_in && inc0 - b.x < r_in) { res[0] = 4 * tid + 0; res[1] = r_in - (inc0 - b.x); }
  }
  __syncthreads();
  bucket = res[0];
  r_out = res[1];
}

// ---------------- Kernel 2: radix-select histogram pass (parallel, 1024 blocks) ---
template <int PASS>
__global__ __launch_bounds__(256)
void k_hist(const float* __restrict__ probsT, unsigned* __restrict__ ghist) {
  __shared__ unsigned h[4][256];
  __shared__ unsigned res[2];
  const int tid = threadIdx.x, wv = tid >> 6;
  const int e = blockIdx.x >> 4;
  const int seg = blockIdx.x & (SEG - 1);
  h[0][tid] = 0; h[1][tid] = 0; h[2][tid] = 0; h[3][tid] = 0;

  unsigned pfx = 0, r = KSEL;
#pragma unroll
  for (int p = 0; p < PASS; ++p) {
    unsigned b, rn;
    pick_scan(ghist + ((size_t)p * NE + e) * 256, r, b, rn, res);
    pfx |= b << (24 - 8 * p);
    r = rn;
  }
  __syncthreads();

  const unsigned hm = PASS ? (0xFFFFFFFFu << (32 - 8 * PASS)) : 0u;
  const int shift = 24 - 8 * PASS;
  const float4* col = (const float4*)(probsT + (size_t)e * GS + seg * SEGLEN);
#pragma unroll
  for (int i = 0; i < SEGLEN / 1024; ++i) {
    float4 v = col[i * 256 + tid];
    unsigned k0 = __float_as_uint(v.x), k1 = __float_as_uint(v.y);
    unsigned k2 = __float_as_uint(v.z), k3 = __float_as_uint(v.w);
    if (PASS == 0 || (k0 & hm) == pfx) atomicAdd(&h[wv][(k0 >> shift) & 255], 1u);
    if (PASS == 0 || (k1 & hm) == pfx) atomicAdd(&h[wv][(k1 >> shift) & 255], 1u);
    if (PASS == 0 || (k2 & hm) == pfx) atomicAdd(&h[wv][(k2 >> shift) & 255], 1u);
    if (PASS == 0 || (k3 & hm) == pfx) atomicAdd(&h[wv][(k3 >> shift) & 255], 1u);
  }
  __syncthreads();
  unsigned c = h[0][tid] + h[1][tid] + h[2][tid] + h[3][tid];
  if (c) atomicAdd(&ghist[((size_t)PASS * NE + e) * 256 + tid], c);
}

// ---------------- Kernel 3: threshold + definite count + candidate collection -----
__global__ __launch_bounds__(256)
void k_cand(const float* __restrict__ probsT, const unsigned* __restrict__ ghist,
            const float* __restrict__ temp, unsigned* __restrict__ defCnt,
            unsigned* __restrict__ candCnt, int* __restrict__ candIdx,
            float* __restrict__ thrHiA) {
  __shared__ unsigned res[2];
  const int tid = threadIdx.x;
  const int e = blockIdx.x >> 4;
  const int seg = blockIdx.x & (SEG - 1);

  unsigned pfx = 0, r = KSEL;
#pragma unroll
  for (int p = 0; p < 4; ++p) {
    unsigned b, rn;
    pick_scan(ghist + ((size_t)p * NE + e) * 256, r, b, rn, res);
    pfx |= b << (24 - 8 * p);
    r = rn;
  }
  const float thrv = __uint_as_float(pfx);
  float st = temp[0];
  if (st < 0.1f) st = 0.1f;
  const float rel = 2.0e-3f / st;          // >=100x margin over gemm error (~1e-5)
  const float hi = thrv * (1.0f + rel);
  const float lo = thrv * (1.0f - rel);
  if (tid == 0 && seg == 0) thrHiA[e] = hi;

  const float* col = probsT + (size_t)e * GS + seg * SEGLEN;
  for (int i = 0; i < SEGLEN / 256; ++i) {
    const int t = i * 256 + tid;
    const float p = col[t];
    if (p > hi) {
      atomicAdd(&defCnt[e], 1u);
    } else if (p >= lo) {
      unsigned pos = atomicAdd(&candCnt[e], 1u);
      if (pos < CAP) candIdx[e * CAP + pos] = seg * SEGLEN + t;
    }
  }
}

// ---------------- Kernel 4: exact fp64 recompute of candidate probabilities -------
__global__ __launch_bounds__(256)
void k_repair(const float* __restrict__ x, const float* __restrict__ w,
              const float* __restrict__ bias, const float* __restrict__ temp,
              const unsigned* __restrict__ candCnt, const int* __restrict__ candIdx,
              double* __restrict__ candKey) {
  __shared__ double red[4][64];
  const int e = blockIdx.x >> 3;
  const int chunk = blockIdx.x & 7;
  const int tid = threadIdx.x;
  const int ee = tid & 63, q = tid >> 6;
  const int cnt = (int)min(candCnt[e], (unsigned)CAP);

  double st = (double)temp[0];
  if (st < 0.1) st = 0.1;
  const double inv_t = 1.0 / st;

  for (int i = chunk; i < cnt; i += 8) {
    const int t = candIdx[e * CAP + i];
    const float* xr = x + (size_t)t * DM;
    double s = 0.0;
    for (int k = q * 256; k < q * 256 + 256; ++k)
      s += (double)xr[k] * (double)w[(size_t)k * NE + ee];
    red[q][ee] = s;
    __syncthreads();
    if (tid < 64) {
      double l = (red[0][tid] + red[1][tid] + red[2][tid] + red[3][tid] +
                  (double)bias[tid]) * inv_t;
      double m = l;
#pragma unroll
      for (int off = 1; off < 64; off <<= 1) m = fmax(m, __shfl_xor(m, off));
      double ex = exp(l - m);
      double ss = ex;
#pragma unroll
      for (int off = 1; off < 64; off <<= 1) ss += __shfl_xor(ss, off);
      if (tid == e) candKey[e * CAP + i] = ex / ss;
    }
    __syncthreads();
  }
}

// ---------------- Kernel 5: exact selection among candidates (rank, deselect) -----
__global__ __launch_bounds__(256)
void k_rank(const unsigned* __restrict__ defCnt, const unsigned* __restrict__ candCnt,
            int* __restrict__ candIdx, const double* __restrict__ candKey) {
  __shared__ double kd[CAP];
  __shared__ int ti[CAP];
  const int e = blockIdx.x, tid = threadIdx.x;
  const int cnt = (int)min(candCnt[e], (unsigned)CAP);
  const int need = KSEL - (int)defCnt[e];
  for (int i = tid; i < cnt; i += 256) {
    kd[i] = candKey[e * CAP + i];
    ti[i] = candIdx[e * CAP + i];
  }
  __syncthreads();
  for (int i = tid; i < cnt; i += 256) {
    const double ki = kd[i];
    const int tii = ti[i];
    int rank = 0;
    for (int j = 0; j < cnt; ++j)
      rank += (kd[j] > ki) || (kd[j] == ki && ti[j] < tii);
    if (rank >= need) candIdx[e * CAP + i] = -1;   // deselect
  }
}

// ---------------- Kernel 6: dense mask scatter (definite region) + loss -----------
__global__ __launch_bounds__(256)
void k_scatter(const float* __restrict__ probsT, const float* __restrict__ thrHiA,
               float* __restrict__ out) {
  const int gid = blockIdx.x * 256 + threadIdx.x;
  const int base = gid * 4;
  const int e = base >> 15;
  float4 p = *(const float4*)(probsT + (size_t)base);
  const float hi = thrHiA[e];
  float pv[4] = {p.x, p.y, p.z, p.w};
  float mk[4], wt[4];
#pragma unroll
  for (int c = 0; c < 4; ++c) {
    bool sel = pv[c] > hi;
    mk[c] = sel ? 1.0f : 0.0f;
    wt[c] = sel ? pv[c] : 0.0f;
  }
  *(float4*)(out + (size_t)base) = make_float4(mk[0], mk[1], mk[2], mk[3]);
  *(float4*)(out + (size_t)MASK_ELEMS + base) = make_float4(wt[0], wt[1], wt[2], wt[3]);
  if (gid == 0) out[2 * (size_t)MASK_ELEMS] = 0.0f;
}

// ---------------- Kernel 7: apply selected candidates ----------------------------
__global__ __launch_bounds__(256)
void k_apply(const unsigned* __restrict__ candCnt, const int* __restrict__ candIdx,
             const float* __restrict__ probsT, float* __restrict__ out) {
  const int e = blockIdx.x, tid = threadIdx.x;
  const int cnt = (int)min(candCnt[e], (unsigned)CAP);
  for (int i = tid; i < cnt; i += 256) {
    const int t = candIdx[e * CAP + i];
    if (t >= 0) {
      out[(size_t)e * GS + t] = 1.0f;
      out[(size_t)MASK_ELEMS + (size_t)e * GS + t] = probsT[(size_t)e * GS + t];
    }
  }
}

extern "C" void kernel_launch(void* const* d_in, const int* in_sizes, int n_in,
                              void* d_out, int out_size, void* d_ws, size_t ws_size,
                              hipStream_t stream) {
  const float* x    = (const float*)d_in[0];
  const float* gw   = (const float*)d_in[1];
  const float* gb   = (const float*)d_in[2];
  const float* temp = (const float*)d_in[3];

  float* probsT    = (float*)d_ws;
  unsigned* ghist  = (unsigned*)((char*)d_ws + (size_t)MASK_ELEMS * 4);   // 256KB
  unsigned* defCnt = ghist + 4 * NE * 256;                                // 256B
  unsigned* candCnt = defCnt + NE;                                        // 256B
  float* thrHiA    = (float*)(candCnt + NE);                              // 256B
  int* candIdx     = (int*)(thrHiA + NE);                                 // 512KB
  double* candKey  = (double*)(candIdx + NE * CAP);                       // 1MB
  unsigned short* wph = (unsigned short*)(candKey + NE * CAP);            // 3x128KB
  unsigned short* wpm = wph + DM * NE;
  unsigned short* wpl = wpm + DM * NE;

  hipMemsetAsync(ghist, 0, (4 * NE * 256 + 2 * NE) * sizeof(unsigned), stream);
  k_split<<<DM * NE / 256, 256, 0, stream>>>(gw, wph, wpm, wpl);
  k_gemm_softmax<<<GS / 16, 64, 0, stream>>>(x, wph, wpm, wpl, gb, temp, probsT);
  k_hist<0><<<NE * SEG, 256, 0, stream>>>(probsT, ghist);
  k_hist<1><<<NE * SEG, 256, 0, stream>>>(probsT, ghist);
  k_hist<2><<<NE * SEG, 256, 0, stream>>>(probsT, ghist);
  k_hist<3><<<NE * SEG, 256, 0, stream>>>(probsT, ghist);
  k_cand<<<NE * SEG, 256, 0, stream>>>(probsT, ghist, temp, defCnt, candCnt,
                                       candIdx, thrHiA);
  k_repair<<<NE * 8, 256, 0, stream>>>(x, gw, gb, temp, candCnt, candIdx, candKey);
  k_rank<<<NE, 256, 0, stream>>>(defCnt, candCnt, candIdx, candKey);
  k_scatter<<<MASK_ELEMS / 1024, 256, 0, stream>>>(probsT, thrHiA, (float*)d_out);
  k_apply<<<NE, 256, 0, stream>>>(candCnt, candIdx, probsT, (float*)d_out);
}

// Round 13
// 278.116 us; speedup vs baseline: 1.2437x; 1.2437x over previous
//
#include <hip/hip_runtime.h>
#include <math.h>

#define NG 8
#define SEQ 4096
#define DM 1024
#define NE 64
#define GS (NG * SEQ)          // 32768 tokens
#define KSEL 1024              // expert capacity
#define MASK_ELEMS (NE * GS)   // 2097152
#define SEG 16
#define SEGLEN (GS / SEG)
#define CAP 2048               // max repair candidates per expert
#define AST 40                 // A-plane LDS row stride in ushorts

typedef __attribute__((ext_vector_type(8))) short short8;
typedef __attribute__((ext_vector_type(4))) float f32x4;

__device__ __forceinline__ unsigned short f2bf(float v) {   // RN-even
  unsigned u = __float_as_uint(v);
  return (unsigned short)((u + 0x7FFFu + ((u >> 16) & 1u)) >> 16);
}
__device__ __forceinline__ float bf2f(unsigned short h) {
  return __uint_as_float(((unsigned)h) << 16);
}

// ---------------- Kernel 0: pre-split gate weights into 2 transposed bf16 planes --
__global__ __launch_bounds__(256)
void k_split(const float* __restrict__ w, unsigned short* __restrict__ wph,
             unsigned short* __restrict__ wpm) {
  const int t = blockIdx.x * 256 + threadIdx.x;   // 65536 = 1024k x 64e
  const int k = t >> 6, e = t & 63;
  float v = w[t];
  unsigned short h = f2bf(v); float r = v - bf2f(h);
  const int o = e * 1024 + k;                      // transposed [e][k]
  wph[o] = h; wpm[o] = f2bf(r);
}

// ---------------- Kernel 1: bf16x2 MFMA GEMM (fp32 acc) + fp32 softmax ------------
// 1 wave/block, 16 tokens x 64 experts. B ping-pong PREFETCHED into registers one
// tile early (round-12 regression: inline B loads serialized at L3 latency). x via
// nontemporal loads so B planes stay L2-resident. Boundary exactness comes from the
// fp64 repair pass, not the GEMM (error ~1e-4/temp << window 2e-3/temp).
__global__ __launch_bounds__(64, 2)
void k_gemm_softmax(const float* __restrict__ x,
                    const unsigned short* __restrict__ wph,
                    const unsigned short* __restrict__ wpm,
                    const float* __restrict__ bias, const float* __restrict__ temp,
                    float* __restrict__ probsT) {
  __shared__ __align__(16) unsigned short Ah[2][16 * AST], Am[2][16 * AST];
  __shared__ float Lt[16][68];
  __shared__ float Pt[64][20];

  const int lane = threadIdx.x;
  const int lrow = lane & 15;          // A-row / B-col / D-col
  const int g = lane >> 4;             // k-slot group (8 k each)
  const int m0 = blockIdx.x * 16;

  // --- probes: C/D (lane,reg)->(i,j) for mfma_f32_16x16x32_bf16 (exact ints) ---
  int irow[4], jcol[4];
  {
    union { unsigned short u[8]; short8 v; } ar, on;
#pragma unroll
    for (int j = 0; j < 8; ++j) { ar.u[j] = f2bf((float)lrow); on.u[j] = 0x3F80u; }
    f32x4 z = {0.f, 0.f, 0.f, 0.f};
    f32x4 p1 = __builtin_amdgcn_mfma_f32_16x16x32_bf16(ar.v, on.v, z, 0, 0, 0);
    f32x4 p2 = __builtin_amdgcn_mfma_f32_16x16x32_bf16(on.v, ar.v, z, 0, 0, 0);
#pragma unroll
    for (int b = 0; b < 4; ++b) {
      irow[b] = ((int)p1[b]) >> 5;   // D = 32*i
      jcol[b] = ((int)p2[b]) >> 5;   // D = 32*j
    }
  }

  f32x4 acc[4];
#pragma unroll
  for (int cb = 0; cb < 4; ++cb) acc[cb] = (f32x4){0.f, 0.f, 0.f, 0.f};

  f32x4 rA0, rA1;
  short8 bhA[4], bmA[4], bhB[4], bmB[4];         // B regs, ping-pong per tile
  const int arow = lane >> 2, af = lane & 3;     // A staging decode (8 consec k)
  const int aoff = arow * AST + af * 8;          // ushort elem offset (16B aligned)
  const int foff = lrow * AST + g * 8;           // A-frag read offset
  const int boff = lrow * 1024 + g * 8;          // B plane base (cb adds 16*1024)

#define LOADA(t)                                                                     \
  {                                                                                  \
    const float* ap = x + (size_t)(m0 + arow) * DM + (t) * 32 + af * 8;              \
    rA0 = __builtin_nontemporal_load((const f32x4*)ap);                              \
    rA1 = __builtin_nontemporal_load(((const f32x4*)ap) + 1);                        \
  }

#define SPLITA(bi)                                                                   \
  {                                                                                  \
    union { unsigned short u[8]; short8 v; } ph, pm;                                 \
    _Pragma("unroll")                                                                \
    for (int j = 0; j < 8; ++j) {                                                    \
      float v0 = (j < 4) ? rA0[j] : rA1[j - 4];                                      \
      unsigned short h_ = f2bf(v0); float r_ = v0 - bf2f(h_);                        \
      ph.u[j] = h_; pm.u[j] = f2bf(r_);                                              \
    }                                                                                \
    *(short8*)(&Ah[bi][aoff]) = ph.v;                                                \
    *(short8*)(&Am[bi][aoff]) = pm.v;                                                \
  }

#define LOADB(t, bh, bm)                                                             \
  {                                                                                  \
    _Pragma("unroll")                                                                \
    for (int cb = 0; cb < 4; ++cb) {                                                 \
      const size_t bo = (size_t)boff + cb * 16 * 1024 + (t) * 32;                    \
      bh[cb] = *(const short8*)(wph + bo);                                           \
      bm[cb] = *(const short8*)(wpm + bo);                                           \
    }                                                                                \
  }

#define MFMA_TILE(bi, bh, bm)                                                        \
  {                                                                                  \
    short8 ah_ = *(const short8*)(&Ah[bi][foff]);                                    \
    short8 am_ = *(const short8*)(&Am[bi][foff]);                                    \
    __builtin_amdgcn_s_setprio(1);                                                   \
    _Pragma("unroll")                                                                \
    for (int cb = 0; cb < 4; ++cb) {                                                 \
      acc[cb] = __builtin_amdgcn_mfma_f32_16x16x32_bf16(ah_, bh[cb], acc[cb], 0, 0, 0); \
      acc[cb] = __builtin_amdgcn_mfma_f32_16x16x32_bf16(am_, bh[cb], acc[cb], 0, 0, 0); \
      acc[cb] = __builtin_amdgcn_mfma_f32_16x16x32_bf16(ah_, bm[cb], acc[cb], 0, 0, 0); \
    }                                                                                \
    __builtin_amdgcn_s_setprio(0);                                                   \
  }

  LOADA(0);
  SPLITA(0);
  LOADA(1);
  LOADB(0, bhA, bmA);

  for (int tt = 0; tt < 32; tt += 2) {
    LOADB(tt + 1, bhB, bmB);          // B prefetch: hides under split + MFMA below
    SPLITA(1);                        // stage A(tt+1) from rA
    if (tt + 2 < 32) LOADA(tt + 2);   // A prefetch
    MFMA_TILE(0, bhA, bmA);           // tile tt (consumes prefetched bhA)
    if (tt + 2 < 32) {
      LOADB(tt + 2, bhA, bmA);        // B prefetch for tile tt+2
      SPLITA(0);                      // stage A(tt+2)
      LOADA(tt + 3);
    }
    MFMA_TILE(1, bhB, bmB);           // tile tt+1
  }

#undef LOADA
#undef SPLITA
#undef LOADB
#undef MFMA_TILE

  // --- canonical Lt[token][expert] (fp32) via probe-measured mapping ---
#pragma unroll
  for (int cb = 0; cb < 4; ++cb)
#pragma unroll
    for (int b = 0; b < 4; ++b)
      Lt[irow[b]][cb * 16 + jcol[b]] = acc[cb][b];

  // --- fp32 softmax ---
  {
    float st = temp[0];
    if (st < 0.1f) st = 0.1f;
    const float inv_t = 1.0f / st;
    const int tt = lane >> 2, q = lane & 3;
    float l[16];
    float mx = -1.0e30f;
#pragma unroll
    for (int j = 0; j < 16; ++j) {
      l[j] = (Lt[tt][q * 16 + j] + bias[q * 16 + j]) * inv_t;
      mx = fmaxf(mx, l[j]);
    }
    mx = fmaxf(mx, __shfl_xor(mx, 1));
    mx = fmaxf(mx, __shfl_xor(mx, 2));
    float p[16], s = 0.0f;
#pragma unroll
    for (int j = 0; j < 16; ++j) { p[j] = __expf(l[j] - mx); s += p[j]; }
    s += __shfl_xor(s, 1);
    s += __shfl_xor(s, 2);
    const float invs = 1.0f / s;
#pragma unroll
    for (int j = 0; j < 16; ++j) Pt[q * 16 + j][tt] = p[j] * invs;
  }

  // --- expert-major store: lane = expert ---
  {
#pragma unroll
    for (int c2 = 0; c2 < 4; ++c2) {
      *(float4*)(probsT + (size_t)lane * GS + m0 + c2 * 4) =
          *(const float4*)(&Pt[lane][c2 * 4]);
    }
  }
}

// ------------- cooperative bucket pick from a 256-bin histogram (block-wide) ------
__device__ __forceinline__ void pick_scan(const unsigned* __restrict__ bins,
                                          unsigned r_in, unsigned& bucket,
                                          unsigned& r_out, unsigned* res) {
  __syncthreads();
  const int tid = threadIdx.x;
  if (tid < 64) {
    uint4 b = ((const uint4*)bins)[tid];
    unsigned s3 = b.w, s2 = b.z + s3, s1 = b.y + s2, s0 = b.x + s1;
    unsigned suf = s0;
#pragma unroll
    for (int off = 1; off < 64; off <<= 1) {
      unsigned t = __shfl_down(suf, off);
      if (tid + off < 64) suf += t;
    }
    unsigned above = suf - s0;
    unsigned inc0 = above + s0, inc1 = above + s1, inc2 = above + s2, inc3 = above + s3;
    if (inc3 >= r_in && inc3 - b.w < r_in) { res[0] = 4 * tid + 3; res[1] = r_in - (inc3 - b.w); }
    if (inc2 >= r_in && inc2 - b.z < r_in) { res[0] = 4 * tid + 2; res[1] = r_in - (inc2 - b.z); }
    if (inc1 >= r_in && inc1 - b.y < r_in) { res[0] = 4 * tid + 1; res[1] = r_in - (inc1 - b.y); }
    if (inc0 >= r_in && inc0 - b.x < r_in) { res[0] = 4 * tid + 0; res[1] = r_in - (inc0 - b.x); }
  }
  __syncthreads();
  bucket = res[0];
  r_out = res[1];
}

// ---------------- Kernel 2: radix-select histogram pass (parallel, 1024 blocks) ---
template <int PASS>
__global__ __launch_bounds__(256)
void k_hist(const float* __restrict__ probsT, unsigned* __restrict__ ghist) {
  __shared__ unsigned h[4][256];
  __shared__ unsigned res[2];
  const int tid = threadIdx.x, wv = tid >> 6;
  const int e = blockIdx.x >> 4;
  const int seg = blockIdx.x & (SEG - 1);
  h[0][tid] = 0; h[1][tid] = 0; h[2][tid] = 0; h[3][tid] = 0;

  unsigned pfx = 0, r = KSEL;
#pragma unroll
  for (int p = 0; p < PASS; ++p) {
    unsigned b, rn;
    pick_scan(ghist + ((size_t)p * NE + e) * 256, r, b, rn, res);
    pfx |= b << (24 - 8 * p);
    r = rn;
  }
  __syncthreads();

  const unsigned hm = PASS ? (0xFFFFFFFFu << (32 - 8 * PASS)) : 0u;
  const int shift = 24 - 8 * PASS;
  const float4* col = (const float4*)(probsT + (size_t)e * GS + seg * SEGLEN);
#pragma unroll
  for (int i = 0; i < SEGLEN / 1024; ++i) {
    float4 v = col[i * 256 + tid];
    unsigned k0 = __float_as_uint(v.x), k1 = __float_as_uint(v.y);
    unsigned k2 = __float_as_uint(v.z), k3 = __float_as_uint(v.w);
    if (PASS == 0 || (k0 & hm) == pfx) atomicAdd(&h[wv][(k0 >> shift) & 255], 1u);
    if (PASS == 0 || (k1 & hm) == pfx) atomicAdd(&h[wv][(k1 >> shift) & 255], 1u);
    if (PASS == 0 || (k2 & hm) == pfx) atomicAdd(&h[wv][(k2 >> shift) & 255], 1u);
    if (PASS == 0 || (k3 & hm) == pfx) atomicAdd(&h[wv][(k3 >> shift) & 255], 1u);
  }
  __syncthreads();
  unsigned c = h[0][tid] + h[1][tid] + h[2][tid] + h[3][tid];
  if (c) atomicAdd(&ghist[((size_t)PASS * NE + e) * 256 + tid], c);
}

// ---------------- Kernel 3: threshold + definite count + candidate collection -----
__global__ __launch_bounds__(256)
void k_cand(const float* __restrict__ probsT, const unsigned* __restrict__ ghist,
            const float* __restrict__ temp, unsigned* __restrict__ defCnt,
            unsigned* __restrict__ candCnt, int* __restrict__ candIdx,
            float* __restrict__ thrHiA) {
  __shared__ unsigned res[2];
  const int tid = threadIdx.x;
  const int e = blockIdx.x >> 4;
  const int seg = blockIdx.x & (SEG - 1);

  unsigned pfx = 0, r = KSEL;
#pragma unroll
  for (int p = 0; p < 4; ++p) {
    unsigned b, rn;
    pick_scan(ghist + ((size_t)p * NE + e) * 256, r, b, rn, res);
    pfx |= b << (24 - 8 * p);
    r = rn;
  }
  const float thrv = __uint_as_float(pfx);
  float st = temp[0];
  if (st < 0.1f) st = 0.1f;
  const float rel = 2.0e-3f / st;          // ~20x margin over gemm error (~1e-4/st)
  const float hi = thrv * (1.0f + rel);
  const float lo = thrv * (1.0f - rel);
  if (tid == 0 && seg == 0) thrHiA[e] = hi;

  const float* col = probsT + (size_t)e * GS + seg * SEGLEN;
  for (int i = 0; i < SEGLEN / 256; ++i) {
    const int t = i * 256 + tid;
    const float p = col[t];
    if (p > hi) {
      atomicAdd(&defCnt[e], 1u);
    } else if (p >= lo) {
      unsigned pos = atomicAdd(&candCnt[e], 1u);
      if (pos < CAP) candIdx[e * CAP + pos] = seg * SEGLEN + t;
    }
  }
}

// ---------------- Kernel 4: exact fp64 recompute of candidate probabilities -------
__global__ __launch_bounds__(256)
void k_repair(const float* __restrict__ x, const float* __restrict__ w,
              const float* __restrict__ bias, const float* __restrict__ temp,
              const unsigned* __restrict__ candCnt, const int* __restrict__ candIdx,
              double* __restrict__ candKey) {
  __shared__ double red[4][64];
  const int e = blockIdx.x >> 4;
  const int chunk = blockIdx.x & 15;
  const int tid = threadIdx.x;
  const int ee = tid & 63, q = tid >> 6;
  const int cnt = (int)min(candCnt[e], (unsigned)CAP);

  double st = (double)temp[0];
  if (st < 0.1) st = 0.1;
  const double inv_t = 1.0 / st;

  for (int i = chunk; i < cnt; i += 16) {
    const int t = candIdx[e * CAP + i];
    const float* xr = x + (size_t)t * DM;
    double s0 = 0.0, s1 = 0.0, s2 = 0.0, s3 = 0.0;
    const int kb = q * 256;
    for (int k = kb; k < kb + 256; k += 4) {
      s0 += (double)xr[k + 0] * (double)w[(size_t)(k + 0) * NE + ee];
      s1 += (double)xr[k + 1] * (double)w[(size_t)(k + 1) * NE + ee];
      s2 += (double)xr[k + 2] * (double)w[(size_t)(k + 2) * NE + ee];
      s3 += (double)xr[k + 3] * (double)w[(size_t)(k + 3) * NE + ee];
    }
    red[q][ee] = (s0 + s1) + (s2 + s3);
    __syncthreads();
    if (tid < 64) {
      double l = (red[0][tid] + red[1][tid] + red[2][tid] + red[3][tid] +
                  (double)bias[tid]) * inv_t;
      double m = l;
#pragma unroll
      for (int off = 1; off < 64; off <<= 1) m = fmax(m, __shfl_xor(m, off));
      double ex = exp(l - m);
      double ss = ex;
#pragma unroll
      for (int off = 1; off < 64; off <<= 1) ss += __shfl_xor(ss, off);
      if (tid == e) candKey[e * CAP + i] = ex / ss;
    }
    __syncthreads();
  }
}

// ---------------- Kernel 5: exact selection among candidates (rank, deselect) -----
__global__ __launch_bounds__(256)
void k_rank(const unsigned* __restrict__ defCnt, const unsigned* __restrict__ candCnt,
            int* __restrict__ candIdx, const double* __restrict__ candKey) {
  __shared__ double kd[CAP];
  __shared__ int ti[CAP];
  const int e = blockIdx.x, tid = threadIdx.x;
  const int cnt = (int)min(candCnt[e], (unsigned)CAP);
  const int need = KSEL - (int)defCnt[e];
  for (int i = tid; i < cnt; i += 256) {
    kd[i] = candKey[e * CAP + i];
    ti[i] = candIdx[e * CAP + i];
  }
  __syncthreads();
  for (int i = tid; i < cnt; i += 256) {
    const double ki = kd[i];
    const int tii = ti[i];
    int rank = 0;
    for (int j = 0; j < cnt; ++j)
      rank += (kd[j] > ki) || (kd[j] == ki && ti[j] < tii);
    if (rank >= need) candIdx[e * CAP + i] = -1;   // deselect
  }
}

// ---------------- Kernel 6: dense mask scatter (definite region) + loss -----------
__global__ __launch_bounds__(256)
void k_scatter(const float* __restrict__ probsT, const float* __restrict__ thrHiA,
               float* __restrict__ out) {
  const int gid = blockIdx.x * 256 + threadIdx.x;
  const int base = gid * 4;
  const int e = base >> 15;
  float4 p = *(const float4*)(probsT + (size_t)base);
  const float hi = thrHiA[e];
  float pv[4] = {p.x, p.y, p.z, p.w};
  float mk[4], wt[4];
#pragma unroll
  for (int c = 0; c < 4; ++c) {
    bool sel = pv[c] > hi;
    mk[c] = sel ? 1.0f : 0.0f;
    wt[c] = sel ? pv[c] : 0.0f;
  }
  *(float4*)(out + (size_t)base) = make_float4(mk[0], mk[1], mk[2], mk[3]);
  *(float4*)(out + (size_t)MASK_ELEMS + base) = make_float4(wt[0], wt[1], wt[2], wt[3]);
  if (gid == 0) out[2 * (size_t)MASK_ELEMS] = 0.0f;
}

// ---------------- Kernel 7: apply selected candidates ----------------------------
__global__ __launch_bounds__(256)
void k_apply(const unsigned* __restrict__ candCnt, const int* __restrict__ candIdx,
             const float* __restrict__ probsT, float* __restrict__ out) {
  const int e = blockIdx.x, tid = threadIdx.x;
  const int cnt = (int)min(candCnt[e], (unsigned)CAP);
  for (int i = tid; i < cnt; i += 256) {
    const int t = candIdx[e * CAP + i];
    if (t >= 0) {
      out[(size_t)e * GS + t] = 1.0f;
      out[(size_t)MASK_ELEMS + (size_t)e * GS + t] = probsT[(size_t)e * GS + t];
    }
  }
}

extern "C" void kernel_launch(void* const* d_in, const int* in_sizes, int n_in,
                              void* d_out, int out_size, void* d_ws, size_t ws_size,
                              hipStream_t stream) {
  const float* x    = (const float*)d_in[0];
  const float* gw   = (const float*)d_in[1];
  const float* gb   = (const float*)d_in[2];
  const float* temp = (const float*)d_in[3];

  float* probsT    = (float*)d_ws;
  unsigned* ghist  = (unsigned*)((char*)d_ws + (size_t)MASK_ELEMS * 4);   // 256KB
  unsigned* defCnt = ghist + 4 * NE * 256;                                // 256B
  unsigned* candCnt = defCnt + NE;                                        // 256B
  float* thrHiA    = (float*)(candCnt + NE);                              // 256B
  int* candIdx     = (int*)(thrHiA + NE);                                 // 512KB
  double* candKey  = (double*)(candIdx + NE * CAP);                       // 1MB
  unsigned short* wph = (unsigned short*)(candKey + NE * CAP);            // 2x128KB
  unsigned short* wpm = wph + DM * NE;

  hipMemsetAsync(ghist, 0, (4 * NE * 256 + 2 * NE) * sizeof(unsigned), stream);
  k_split<<<DM * NE / 256, 256, 0, stream>>>(gw, wph, wpm);
  k_gemm_softmax<<<GS / 16, 64, 0, stream>>>(x, wph, wpm, gb, temp, probsT);
  k_hist<0><<<NE * SEG, 256, 0, stream>>>(probsT, ghist);
  k_hist<1><<<NE * SEG, 256, 0, stream>>>(probsT, ghist);
  k_hist<2><<<NE * SEG, 256, 0, stream>>>(probsT, ghist);
  k_hist<3><<<NE * SEG, 256, 0, stream>>>(probsT, ghist);
  k_cand<<<NE * SEG, 256, 0, stream>>>(probsT, ghist, temp, defCnt, candCnt,
                                       candIdx, thrHiA);
  k_repair<<<NE * 16, 256, 0, stream>>>(x, gw, gb, temp, candCnt, candIdx, candKey);
  k_rank<<<NE, 256, 0, stream>>>(defCnt, candCnt, candIdx, candKey);
  k_scatter<<<MASK_ELEMS / 1024, 256, 0, stream>>>(probsT, thrHiA, (float*)d_out);
  k_apply<<<NE, 256, 0, stream>>>(candCnt, candIdx, probsT, (float*)d_out);
}

// Round 14
// 149.848 us; speedup vs baseline: 2.3082x; 1.8560x over previous
//
#include <hip/hip_runtime.h>
#include <math.h>

#define NG 8
#define SEQ 4096
#define DM 1024
#define NE 64
#define GS (NG * SEQ)          // 32768 tokens
#define KSEL 1024              // expert capacity
#define MASK_ELEMS (NE * GS)   // 2097152
#define SEG 16
#define SEGLEN (GS / SEG)
#define CAP 2048               // max repair candidates per expert
#define AST 40                 // A-plane LDS row stride in ushorts

typedef __attribute__((ext_vector_type(8))) short short8;
typedef __attribute__((ext_vector_type(4))) float f32x4;

__device__ __forceinline__ unsigned short f2bf(float v) {   // RN-even
  unsigned u = __float_as_uint(v);
  return (unsigned short)((u + 0x7FFFu + ((u >> 16) & 1u)) >> 16);
}
__device__ __forceinline__ float bf2f(unsigned short h) {
  return __uint_as_float(((unsigned)h) << 16);
}

// ---------------- Kernel 0: pre-split gate weights into 2 transposed bf16 planes --
__global__ __launch_bounds__(256)
void k_split(const float* __restrict__ w, unsigned short* __restrict__ wph,
             unsigned short* __restrict__ wpm) {
  const int t = blockIdx.x * 256 + threadIdx.x;   // 65536 = 1024k x 64e
  const int k = t >> 6, e = t & 63;
  float v = w[t];
  unsigned short h = f2bf(v); float r = v - bf2f(h);
  const int o = e * 1024 + k;                      // transposed [e][k]
  wph[o] = h; wpm[o] = f2bf(r);
}

// ---------------- Kernel 1: bf16x2 MFMA GEMM (fp32 acc) + fp32 softmax ------------
__global__ __launch_bounds__(64, 2)
void k_gemm_softmax(const float* __restrict__ x,
                    const unsigned short* __restrict__ wph,
                    const unsigned short* __restrict__ wpm,
                    const float* __restrict__ bias, const float* __restrict__ temp,
                    float* __restrict__ probsT) {
  __shared__ __align__(16) unsigned short Ah[2][16 * AST], Am[2][16 * AST];
  __shared__ float Lt[16][68];
  __shared__ float Pt[64][20];

  const int lane = threadIdx.x;
  const int lrow = lane & 15;          // A-row / B-col / D-col
  const int g = lane >> 4;             // k-slot group (8 k each)
  const int m0 = blockIdx.x * 16;

  // --- probes: C/D (lane,reg)->(i,j) for mfma_f32_16x16x32_bf16 (exact ints) ---
  int irow[4], jcol[4];
  {
    union { unsigned short u[8]; short8 v; } ar, on;
#pragma unroll
    for (int j = 0; j < 8; ++j) { ar.u[j] = f2bf((float)lrow); on.u[j] = 0x3F80u; }
    f32x4 z = {0.f, 0.f, 0.f, 0.f};
    f32x4 p1 = __builtin_amdgcn_mfma_f32_16x16x32_bf16(ar.v, on.v, z, 0, 0, 0);
    f32x4 p2 = __builtin_amdgcn_mfma_f32_16x16x32_bf16(on.v, ar.v, z, 0, 0, 0);
#pragma unroll
    for (int b = 0; b < 4; ++b) {
      irow[b] = ((int)p1[b]) >> 5;   // D = 32*i
      jcol[b] = ((int)p2[b]) >> 5;   // D = 32*j
    }
  }

  f32x4 acc[4];
#pragma unroll
  for (int cb = 0; cb < 4; ++cb) acc[cb] = (f32x4){0.f, 0.f, 0.f, 0.f};

  f32x4 rA0, rA1;
  short8 bhA[4], bmA[4], bhB[4], bmB[4];         // B regs, ping-pong per tile
  const int arow = lane >> 2, af = lane & 3;     // A staging decode (8 consec k)
  const int aoff = arow * AST + af * 8;          // ushort elem offset (16B aligned)
  const int foff = lrow * AST + g * 8;           // A-frag read offset
  const int boff = lrow * 1024 + g * 8;          // B plane base (cb adds 16*1024)

#define LOADA(t)                                                                     \
  {                                                                                  \
    const float* ap = x + (size_t)(m0 + arow) * DM + (t) * 32 + af * 8;              \
    rA0 = __builtin_nontemporal_load((const f32x4*)ap);                              \
    rA1 = __builtin_nontemporal_load(((const f32x4*)ap) + 1);                        \
  }

#define SPLITA(bi)                                                                   \
  {                                                                                  \
    union { unsigned short u[8]; short8 v; } ph, pm;                                 \
    _Pragma("unroll")                                                                \
    for (int j = 0; j < 8; ++j) {                                                    \
      float v0 = (j < 4) ? rA0[j] : rA1[j - 4];                                      \
      unsigned short h_ = f2bf(v0); float r_ = v0 - bf2f(h_);                        \
      ph.u[j] = h_; pm.u[j] = f2bf(r_);                                              \
    }                                                                                \
    *(short8*)(&Ah[bi][aoff]) = ph.v;                                                \
    *(short8*)(&Am[bi][aoff]) = pm.v;                                                \
  }

#define LOADB(t, bh, bm)                                                             \
  {                                                                                  \
    _Pragma("unroll")                                                                \
    for (int cb = 0; cb < 4; ++cb) {                                                 \
      const size_t bo = (size_t)boff + cb * 16 * 1024 + (t) * 32;                    \
      bh[cb] = *(const short8*)(wph + bo);                                           \
      bm[cb] = *(const short8*)(wpm + bo);                                           \
    }                                                                                \
  }

#define MFMA_TILE(bi, bh, bm)                                                        \
  {                                                                                  \
    short8 ah_ = *(const short8*)(&Ah[bi][foff]);                                    \
    short8 am_ = *(const short8*)(&Am[bi][foff]);                                    \
    __builtin_amdgcn_s_setprio(1);                                                   \
    _Pragma("unroll")                                                                \
    for (int cb = 0; cb < 4; ++cb) {                                                 \
      acc[cb] = __builtin_amdgcn_mfma_f32_16x16x32_bf16(ah_, bh[cb], acc[cb], 0, 0, 0); \
      acc[cb] = __builtin_amdgcn_mfma_f32_16x16x32_bf16(am_, bh[cb], acc[cb], 0, 0, 0); \
      acc[cb] = __builtin_amdgcn_mfma_f32_16x16x32_bf16(ah_, bm[cb], acc[cb], 0, 0, 0); \
    }                                                                                \
    __builtin_amdgcn_s_setprio(0);                                                   \
  }

  LOADA(0);
  SPLITA(0);
  LOADA(1);
  LOADB(0, bhA, bmA);

  for (int tt = 0; tt < 32; tt += 2) {
    LOADB(tt + 1, bhB, bmB);          // B prefetch: hides under split + MFMA below
    SPLITA(1);                        // stage A(tt+1) from rA
    if (tt + 2 < 32) LOADA(tt + 2);   // A prefetch
    MFMA_TILE(0, bhA, bmA);           // tile tt (consumes prefetched bhA)
    if (tt + 2 < 32) {
      LOADB(tt + 2, bhA, bmA);        // B prefetch for tile tt+2
      SPLITA(0);                      // stage A(tt+2)
      LOADA(tt + 3);
    }
    MFMA_TILE(1, bhB, bmB);           // tile tt+1
  }

#undef LOADA
#undef SPLITA
#undef LOADB
#undef MFMA_TILE

  // --- canonical Lt[token][expert] (fp32) via probe-measured mapping ---
#pragma unroll
  for (int cb = 0; cb < 4; ++cb)
#pragma unroll
    for (int b = 0; b < 4; ++b)
      Lt[irow[b]][cb * 16 + jcol[b]] = acc[cb][b];

  // --- fp32 softmax ---
  {
    float st = temp[0];
    if (st < 0.1f) st = 0.1f;
    const float inv_t = 1.0f / st;
    const int tt = lane >> 2, q = lane & 3;
    float l[16];
    float mx = -1.0e30f;
#pragma unroll
    for (int j = 0; j < 16; ++j) {
      l[j] = (Lt[tt][q * 16 + j] + bias[q * 16 + j]) * inv_t;
      mx = fmaxf(mx, l[j]);
    }
    mx = fmaxf(mx, __shfl_xor(mx, 1));
    mx = fmaxf(mx, __shfl_xor(mx, 2));
    float p[16], s = 0.0f;
#pragma unroll
    for (int j = 0; j < 16; ++j) { p[j] = __expf(l[j] - mx); s += p[j]; }
    s += __shfl_xor(s, 1);
    s += __shfl_xor(s, 2);
    const float invs = 1.0f / s;
#pragma unroll
    for (int j = 0; j < 16; ++j) Pt[q * 16 + j][tt] = p[j] * invs;
  }

  // --- expert-major store: lane = expert ---
  {
#pragma unroll
    for (int c2 = 0; c2 < 4; ++c2) {
      *(float4*)(probsT + (size_t)lane * GS + m0 + c2 * 4) =
          *(const float4*)(&Pt[lane][c2 * 4]);
    }
  }
}

// ------------- cooperative bucket pick from a 256-bin histogram (block-wide) ------
__device__ __forceinline__ void pick_scan(const unsigned* __restrict__ bins,
                                          unsigned r_in, unsigned& bucket,
                                          unsigned& r_out, unsigned* res) {
  __syncthreads();
  const int tid = threadIdx.x;
  if (tid < 64) {
    uint4 b = ((const uint4*)bins)[tid];
    unsigned s3 = b.w, s2 = b.z + s3, s1 = b.y + s2, s0 = b.x + s1;
    unsigned suf = s0;
#pragma unroll
    for (int off = 1; off < 64; off <<= 1) {
      unsigned t = __shfl_down(suf, off);
      if (tid + off < 64) suf += t;
    }
    unsigned above = suf - s0;
    unsigned inc0 = above + s0, inc1 = above + s1, inc2 = above + s2, inc3 = above + s3;
    if (inc3 >= r_in && inc3 - b.w < r_in) { res[0] = 4 * tid + 3; res[1] = r_in - (inc3 - b.w); }
    if (inc2 >= r_in && inc2 - b.z < r_in) { res[0] = 4 * tid + 2; res[1] = r_in - (inc2 - b.z); }
    if (inc1 >= r_in && inc1 - b.y < r_in) { res[0] = 4 * tid + 1; res[1] = r_in - (inc1 - b.y); }
    if (inc0 >= r_in && inc0 - b.x < r_in) { res[0] = 4 * tid + 0; res[1] = r_in - (inc0 - b.x); }
  }
  __syncthreads();
  bucket = res[0];
  r_out = res[1];
}

// ---------------- Kernel 2: radix-select histogram pass (parallel, 1024 blocks) ---
template <int PASS>
__global__ __launch_bounds__(256)
void k_hist(const float* __restrict__ probsT, unsigned* __restrict__ ghist) {
  __shared__ unsigned h[4][256];
  __shared__ unsigned res[2];
  const int tid = threadIdx.x, wv = tid >> 6;
  const int e = blockIdx.x >> 4;
  const int seg = blockIdx.x & (SEG - 1);
  h[0][tid] = 0; h[1][tid] = 0; h[2][tid] = 0; h[3][tid] = 0;

  unsigned pfx = 0, r = KSEL;
#pragma unroll
  for (int p = 0; p < PASS; ++p) {
    unsigned b, rn;
    pick_scan(ghist + ((size_t)p * NE + e) * 256, r, b, rn, res);
    pfx |= b << (24 - 8 * p);
    r = rn;
  }
  __syncthreads();

  const unsigned hm = PASS ? (0xFFFFFFFFu << (32 - 8 * PASS)) : 0u;
  const int shift = 24 - 8 * PASS;
  const float4* col = (const float4*)(probsT + (size_t)e * GS + seg * SEGLEN);
#pragma unroll
  for (int i = 0; i < SEGLEN / 1024; ++i) {
    float4 v = col[i * 256 + tid];
    unsigned k0 = __float_as_uint(v.x), k1 = __float_as_uint(v.y);
    unsigned k2 = __float_as_uint(v.z), k3 = __float_as_uint(v.w);
    if (PASS == 0 || (k0 & hm) == pfx) atomicAdd(&h[wv][(k0 >> shift) & 255], 1u);
    if (PASS == 0 || (k1 & hm) == pfx) atomicAdd(&h[wv][(k1 >> shift) & 255], 1u);
    if (PASS == 0 || (k2 & hm) == pfx) atomicAdd(&h[wv][(k2 >> shift) & 255], 1u);
    if (PASS == 0 || (k3 & hm) == pfx) atomicAdd(&h[wv][(k3 >> shift) & 255], 1u);
  }
  __syncthreads();
  unsigned c = h[0][tid] + h[1][tid] + h[2][tid] + h[3][tid];
  if (c) atomicAdd(&ghist[((size_t)PASS * NE + e) * 256 + tid], c);
}

// ---------------- Kernel 3: threshold + definite count + candidates (block-agg) ---
// Round-13 lesson: per-token global atomics to 64 adjacent counters serialize on
// shared cache lines (~140us). Aggregate per-block in LDS; ONE atomicAdd per block
// per counter (16/expert), bulk-reserve candIdx slots.
__global__ __launch_bounds__(256)
void k_cand(const float* __restrict__ probsT, const unsigned* __restrict__ ghist,
            const float* __restrict__ temp, unsigned* __restrict__ defCnt,
            unsigned* __restrict__ candCnt, int* __restrict__ candIdx,
            float* __restrict__ thrHiA) {
  __shared__ unsigned res[2];
  __shared__ unsigned locDef, locCand, basePos;
  __shared__ int locIdx[1024];
  const int tid = threadIdx.x;
  const int e = blockIdx.x >> 4;
  const int seg = blockIdx.x & (SEG - 1);

  if (tid == 0) { locDef = 0u; locCand = 0u; }
  // pick_scan opens with __syncthreads -> init visible before any use.
  unsigned pfx = 0, r = KSEL;
#pragma unroll
  for (int p = 0; p < 4; ++p) {
    unsigned b, rn;
    pick_scan(ghist + ((size_t)p * NE + e) * 256, r, b, rn, res);
    pfx |= b << (24 - 8 * p);
    r = rn;
  }
  const float thrv = __uint_as_float(pfx);
  float st = temp[0];
  if (st < 0.1f) st = 0.1f;
  const float rel = 2.0e-3f / st;          // ~20x margin over gemm error (~1e-4/st)
  const float hi = thrv * (1.0f + rel);
  const float lo = thrv * (1.0f - rel);
  if (tid == 0 && seg == 0) thrHiA[e] = hi;

  const float* col = probsT + (size_t)e * GS + seg * SEGLEN;
  for (int i = 0; i < SEGLEN / 256; ++i) {
    const int t = i * 256 + tid;
    const float p = col[t];
    if (p > hi) {
      atomicAdd(&locDef, 1u);                       // LDS atomic
    } else if (p >= lo) {
      unsigned pos = atomicAdd(&locCand, 1u);       // LDS atomic
      if (pos < 1024u) locIdx[pos] = seg * SEGLEN + t;
    }
  }
  __syncthreads();
  if (tid == 0) {
    if (locDef) atomicAdd(&defCnt[e], locDef);
    unsigned lc = min(locCand, 1024u);
    locCand = lc;
    basePos = lc ? atomicAdd(&candCnt[e], lc) : 0u;
  }
  __syncthreads();
  {
    const unsigned lc = locCand, bp = basePos;
    for (unsigned i = tid; i < lc; i += 256) {
      const unsigned gp = bp + i;
      if (gp < CAP) candIdx[e * CAP + gp] = locIdx[i];
    }
  }
}

// ---------------- Kernel 4: exact fp64 recompute of candidate probabilities -------
__global__ __launch_bounds__(256)
void k_repair(const float* __restrict__ x, const float* __restrict__ w,
              const float* __restrict__ bias, const float* __restrict__ temp,
              const unsigned* __restrict__ candCnt, const int* __restrict__ candIdx,
              double* __restrict__ candKey) {
  __shared__ double red[4][64];
  const int e = blockIdx.x >> 4;
  const int chunk = blockIdx.x & 15;
  const int tid = threadIdx.x;
  const int ee = tid & 63, q = tid >> 6;
  const int cnt = (int)min(candCnt[e], (unsigned)CAP);

  double st = (double)temp[0];
  if (st < 0.1) st = 0.1;
  const double inv_t = 1.0 / st;

  for (int i = chunk; i < cnt; i += 16) {
    const int t = candIdx[e * CAP + i];
    const float* xr = x + (size_t)t * DM;
    double s0 = 0.0, s1 = 0.0, s2 = 0.0, s3 = 0.0;
    const int kb = q * 256;
    for (int k = kb; k < kb + 256; k += 4) {
      s0 += (double)xr[k + 0] * (double)w[(size_t)(k + 0) * NE + ee];
      s1 += (double)xr[k + 1] * (double)w[(size_t)(k + 1) * NE + ee];
      s2 += (double)xr[k + 2] * (double)w[(size_t)(k + 2) * NE + ee];
      s3 += (double)xr[k + 3] * (double)w[(size_t)(k + 3) * NE + ee];
    }
    red[q][ee] = (s0 + s1) + (s2 + s3);
    __syncthreads();
    if (tid < 64) {
      double l = (red[0][tid] + red[1][tid] + red[2][tid] + red[3][tid] +
                  (double)bias[tid]) * inv_t;
      double m = l;
#pragma unroll
      for (int off = 1; off < 64; off <<= 1) m = fmax(m, __shfl_xor(m, off));
      double ex = exp(l - m);
      double ss = ex;
#pragma unroll
      for (int off = 1; off < 64; off <<= 1) ss += __shfl_xor(ss, off);
      if (tid == e) candKey[e * CAP + i] = ex / ss;
    }
    __syncthreads();
  }
}

// ---------------- Kernel 5: exact selection among candidates (rank, deselect) -----
__global__ __launch_bounds__(256)
void k_rank(const unsigned* __restrict__ defCnt, const unsigned* __restrict__ candCnt,
            int* __restrict__ candIdx, const double* __restrict__ candKey) {
  __shared__ double kd[CAP];
  __shared__ int ti[CAP];
  const int e = blockIdx.x, tid = threadIdx.x;
  const int cnt = (int)min(candCnt[e], (unsigned)CAP);
  const int need = KSEL - (int)defCnt[e];
  for (int i = tid; i < cnt; i += 256) {
    kd[i] = candKey[e * CAP + i];
    ti[i] = candIdx[e * CAP + i];
  }
  __syncthreads();
  for (int i = tid; i < cnt; i += 256) {
    const double ki = kd[i];
    const int tii = ti[i];
    int rank = 0;
    for (int j = 0; j < cnt; ++j)
      rank += (kd[j] > ki) || (kd[j] == ki && ti[j] < tii);
    if (rank >= need) candIdx[e * CAP + i] = -1;   // deselect
  }
}

// ---------------- Kernel 6: dense mask scatter (definite region) + loss -----------
__global__ __launch_bounds__(256)
void k_scatter(const float* __restrict__ probsT, const float* __restrict__ thrHiA,
               float* __restrict__ out) {
  const int gid = blockIdx.x * 256 + threadIdx.x;
  const int base = gid * 4;
  const int e = base >> 15;
  float4 p = *(const float4*)(probsT + (size_t)base);
  const float hi = thrHiA[e];
  float pv[4] = {p.x, p.y, p.z, p.w};
  float mk[4], wt[4];
#pragma unroll
  for (int c = 0; c < 4; ++c) {
    bool sel = pv[c] > hi;
    mk[c] = sel ? 1.0f : 0.0f;
    wt[c] = sel ? pv[c] : 0.0f;
  }
  *(float4*)(out + (size_t)base) = make_float4(mk[0], mk[1], mk[2], mk[3]);
  *(float4*)(out + (size_t)MASK_ELEMS + base) = make_float4(wt[0], wt[1], wt[2], wt[3]);
  if (gid == 0) out[2 * (size_t)MASK_ELEMS] = 0.0f;
}

// ---------------- Kernel 7: apply selected candidates ----------------------------
__global__ __launch_bounds__(256)
void k_apply(const unsigned* __restrict__ candCnt, const int* __restrict__ candIdx,
             const float* __restrict__ probsT, float* __restrict__ out) {
  const int e = blockIdx.x, tid = threadIdx.x;
  const int cnt = (int)min(candCnt[e], (unsigned)CAP);
  for (int i = tid; i < cnt; i += 256) {
    const int t = candIdx[e * CAP + i];
    if (t >= 0) {
      out[(size_t)e * GS + t] = 1.0f;
      out[(size_t)MASK_ELEMS + (size_t)e * GS + t] = probsT[(size_t)e * GS + t];
    }
  }
}

extern "C" void kernel_launch(void* const* d_in, const int* in_sizes, int n_in,
                              void* d_out, int out_size, void* d_ws, size_t ws_size,
                              hipStream_t stream) {
  const float* x    = (const float*)d_in[0];
  const float* gw   = (const float*)d_in[1];
  const float* gb   = (const float*)d_in[2];
  const float* temp = (const float*)d_in[3];

  float* probsT    = (float*)d_ws;
  unsigned* ghist  = (unsigned*)((char*)d_ws + (size_t)MASK_ELEMS * 4);   // 256KB
  unsigned* defCnt = ghist + 4 * NE * 256;                                // 256B
  unsigned* candCnt = defCnt + NE;                                        // 256B
  float* thrHiA    = (float*)(candCnt + NE);                              // 256B
  int* candIdx     = (int*)(thrHiA + NE);                                 // 512KB
  double* candKey  = (double*)(candIdx + NE * CAP);                       // 1MB
  unsigned short* wph = (unsigned short*)(candKey + NE * CAP);            // 2x128KB
  unsigned short* wpm = wph + DM * NE;

  hipMemsetAsync(ghist, 0, (4 * NE * 256 + 2 * NE) * sizeof(unsigned), stream);
  k_split<<<DM * NE / 256, 256, 0, stream>>>(gw, wph, wpm);
  k_gemm_softmax<<<GS / 16, 64, 0, stream>>>(x, wph, wpm, gb, temp, probsT);
  k_hist<0><<<NE * SEG, 256, 0, stream>>>(probsT, ghist);
  k_hist<1><<<NE * SEG, 256, 0, stream>>>(probsT, ghist);
  k_hist<2><<<NE * SEG, 256, 0, stream>>>(probsT, ghist);
  k_hist<3><<<NE * SEG, 256, 0, stream>>>(probsT, ghist);
  k_cand<<<NE * SEG, 256, 0, stream>>>(probsT, ghist, temp, defCnt, candCnt,
                                       candIdx, thrHiA);
  k_repair<<<NE * 16, 256, 0, stream>>>(x, gw, gb, temp, candCnt, candIdx, candKey);
  k_rank<<<NE, 256, 0, stream>>>(defCnt, candCnt, candIdx, candKey);
  k_scatter<<<MASK_ELEMS / 1024, 256, 0, stream>>>(probsT, thrHiA, (float*)d_out);
  k_apply<<<NE, 256, 0, stream>>>(candCnt, candIdx, probsT, (float*)d_out);
}